// Round 22
// baseline (186.180 us; speedup 1.0000x reference)
//
#include <hip/hip_runtime.h>
#include <hip/hip_bf16.h>
#include <stdint.h>

#define B_ 4
#define T_ 2048
#define D_ 1024
#define H_ 16
#define DK_ 64
#define M_ (B_*T_)   // 8192

typedef __attribute__((ext_vector_type(8))) short bf16x8;
typedef __attribute__((ext_vector_type(4))) short bf16x4;
typedef __attribute__((ext_vector_type(4))) float f32x4;
typedef __hip_bfloat16 bf16;

__device__ __forceinline__ void gld_lds16(const bf16* g, bf16* l) {
  __builtin_amdgcn_global_load_lds((const __attribute__((address_space(1))) void*)g,
                                   (__attribute__((address_space(3))) void*)l,
                                   16, 0, 0);
}
__device__ __forceinline__ void gld_lds16f(const float* g, float* l) {
  __builtin_amdgcn_global_load_lds((const __attribute__((address_space(1))) void*)g,
                                   (__attribute__((address_space(3))) void*)l,
                                   16, 0, 0);
}

__device__ __forceinline__ short bfbits(float f) {
  union { bf16 h; short s; } u; u.h = __float2bfloat16(f); return u.s;
}

// ---------------------------------------------------------------------------
// fp32 -> bf16 convert, WEIGHTS ONLY (round-18 exact)
// ---------------------------------------------------------------------------
__global__ __launch_bounds__(256) void cvt_w(
    const float* __restrict__ wq, const float* __restrict__ wk,
    const float* __restrict__ wv, const float* __restrict__ wo,
    bf16* __restrict__ wqb, bf16* __restrict__ wkb,
    bf16* __restrict__ wvb, bf16* __restrict__ wob) {
  int gid = blockIdx.x * 256 + threadIdx.x;   // 0 .. 1048575 (float4 units)
  int s = gid >> 18, off = gid & 262143;
  const float* src = (s == 0) ? wq : (s == 1) ? wk : (s == 2) ? wv : wo;
  bf16* dst = (s == 0) ? wqb : (s == 1) ? wkb : (s == 2) ? wvb : wob;
  float4 val = reinterpret_cast<const float4*>(src)[off];
  union { ushort4 u; bf16 h[4]; } o;
  o.h[0] = __float2bfloat16(val.x);
  o.h[1] = __float2bfloat16(val.y);
  o.h[2] = __float2bfloat16(val.z);
  o.h[3] = __float2bfloat16(val.w);
  reinterpret_cast<ushort4*>(dst)[off] = o.u;
}

// ---------------------------------------------------------------------------
// Unified QKV projection (round-18 exact): (feature, token) orientation,
// A = weight bf16 via gld_lds, B = raw fp32 tokens via gld_lds, converted
// per-fragment. 2-phase sync. LDS 64 KB.
// ---------------------------------------------------------------------------
__global__ __launch_bounds__(512) void proj_qkv(
    const float* __restrict__ qf, const float* __restrict__ kf, const float* __restrict__ vf,
    const bf16* __restrict__ Wqb, const bf16* __restrict__ Wkb, const bf16* __restrict__ Wvb,
    const float* __restrict__ bq, const float* __restrict__ bk, const float* __restrict__ bv,
    bf16* __restrict__ Qh, bf16* __restrict__ Kh, bf16* __restrict__ Vt) {
  constexpr int K = 1024;
  constexpr int BK = 64;
  __shared__ __align__(16) bf16  As[256 * 64];
  __shared__ __align__(16) float Bsf[128 * 64];

  const int z = blockIdx.z;
  const bf16*  A  = (z == 0) ? Wqb : (z == 1) ? Wkb : Wvb;
  const float* Bf = (z == 0) ? qf : (z == 1) ? kf : vf;
  const float* bias = (z == 0) ? bq : (z == 1) ? bk : bv;
  bf16* out = (z == 0) ? Qh : (z == 1) ? Kh : Vt;
  const float scale = (z == 0) ? 0.125f * 1.4426950408889634f : 1.0f;

  const int bid = blockIdx.x + 32 * blockIdx.y;
  const int bm = bid >> 6;
  const int bn = bid & 63;

  const int tid = threadIdx.x;
  const int w = tid >> 6, l = tid & 63;
  const int wm = w >> 1, wn = w & 1;
  const int lr = l & 15, lk = l >> 4;

  f32x4 acc[4][4] = {};

  for (int k0 = 0; k0 < K; k0 += BK) {
#pragma unroll
    for (int i = 0; i < 4; ++i) {
      int p = i * 512 + tid;
      int row = p >> 3;
      int so = (p & 7) ^ (row & 7);
      gld_lds16(A + (size_t)(bm * 256 + row) * K + k0 + so * 8, &As[p * 8]);
    }
#pragma unroll
    for (int i = 0; i < 4; ++i) {
      int p = i * 512 + tid;
      int row = p >> 4;
      int sc = (p & 15) ^ (row & 15);
      gld_lds16f(Bf + (size_t)(bn * 128 + row) * K + k0 + sc * 4, &Bsf[p * 4]);
    }
    __syncthreads();

#pragma unroll
    for (int kk = 0; kk < 2; ++kk) {
      bf16x8 af[4], bfr[4];
#pragma unroll
      for (int m = 0; m < 4; ++m) {
        int row = wm * 64 + m * 16 + lr;
        int slot = (kk * 4 + lk) ^ (row & 7);
        af[m] = *reinterpret_cast<const bf16x8*>(&As[row * 64 + slot * 8]);
      }
#pragma unroll
      for (int n = 0; n < 4; ++n) {
        int trow = wn * 64 + n * 16 + lr;
        int c0 = kk * 8 + lk * 2;
        int s0 = c0 ^ (trow & 15);
        int s1 = (c0 + 1) ^ (trow & 15);
        f32x4 lo = *reinterpret_cast<const f32x4*>(&Bsf[trow * 64 + s0 * 4]);
        f32x4 hi = *reinterpret_cast<const f32x4*>(&Bsf[trow * 64 + s1 * 4]);
        bf16x8 bb;
        bb[0] = bfbits(lo[0]); bb[1] = bfbits(lo[1]);
        bb[2] = bfbits(lo[2]); bb[3] = bfbits(lo[3]);
        bb[4] = bfbits(hi[0]); bb[5] = bfbits(hi[1]);
        bb[6] = bfbits(hi[2]); bb[7] = bfbits(hi[3]);
        bfr[n] = bb;
      }
      __builtin_amdgcn_s_setprio(1);
#pragma unroll
      for (int m = 0; m < 4; ++m)
#pragma unroll
        for (int n = 0; n < 4; ++n)
          acc[m][n] = __builtin_amdgcn_mfma_f32_16x16x32_bf16(af[m], bfr[n], acc[m][n], 0, 0, 0);
      __builtin_amdgcn_s_setprio(0);
    }
    __syncthreads();
  }

  const int crow0 = bm * 256 + wm * 64;
  const int ccol0 = bn * 128 + wn * 64;
  if (z < 2) {
#pragma unroll
    for (int m = 0; m < 4; ++m) {
#pragma unroll
      for (int n = 0; n < 4; ++n) {
        const int row0 = crow0 + m * 16 + lk * 4;
        const int col = ccol0 + n * 16 + lr;
        bf16x4 pk;
#pragma unroll
        for (int r = 0; r < 4; ++r)
          pk[r] = bfbits((acc[m][n][r] + bias[row0 + r]) * scale);
        size_t idx = (((size_t)(col >> 11) * H_ + (row0 >> 6)) * T_ + (col & (T_ - 1))) * DK_ + (row0 & 63);
        *reinterpret_cast<bf16x4*>(&out[idx]) = pk;
      }
    }
  } else {
#pragma unroll
    for (int m = 0; m < 4; ++m) {
#pragma unroll
      for (int n = 0; n < 4; ++n) {
#pragma unroll
        for (int r = 0; r < 4; ++r) {
          const int row = crow0 + m * 16 + lk * 4 + r;
          const int col = ccol0 + n * 16 + lr;
          float vv = acc[m][n][r] + bias[row];
          size_t idx = (size_t)(col >> 11) * ((size_t)H_ * DK_ * T_) + (size_t)row * T_ + (col & (T_ - 1));
          out[idx] = __float2bfloat16(vv);
        }
      }
    }
  }
}

// ---------------------------------------------------------------------------
// Output GEMM (round-18 exact)
// ---------------------------------------------------------------------------
__global__ __launch_bounds__(512) void gemm_out(const bf16* __restrict__ A,
                                                const bf16* __restrict__ Bm,
                                                const float* __restrict__ bias,
                                                float* __restrict__ Cout) {
  constexpr int K = 1024;
  constexpr int BK = 64;
  __shared__ __align__(16) bf16 As[256 * BK];
  __shared__ __align__(16) bf16 Bs[128 * BK];

  const int bid = blockIdx.x + 32 * blockIdx.y;
  const int xcd = bid & 7, loc = bid >> 3;
  const int bm = xcd * 4 + (loc & 3);
  const int bn = loc >> 2;

  const int tid = threadIdx.x;
  const int w = tid >> 6, l = tid & 63;
  const int wm = w >> 1, wn = w & 1;
  const int lr = l & 15, lk = l >> 4;

  f32x4 acc[4][4] = {};

  for (int k0 = 0; k0 < K; k0 += BK) {
#pragma unroll
    for (int i = 0; i < 4; ++i) {
      int p = i * 512 + tid;
      int row = p >> 3;
      int so = (p & 7) ^ (row & 7);
      gld_lds16(A + (size_t)(bm * 256 + row) * K + k0 + so * 8, &As[p * 8]);
    }
#pragma unroll
    for (int i = 0; i < 2; ++i) {
      int p = i * 512 + tid;
      int row = p >> 3;
      int so = (p & 7) ^ (row & 7);
      gld_lds16(Bm + (size_t)(bn * 128 + row) * K + k0 + so * 8, &Bs[p * 8]);
    }
    __syncthreads();

#pragma unroll
    for (int kk = 0; kk < 2; ++kk) {
      bf16x8 af[4], bfr[4];
#pragma unroll
      for (int m = 0; m < 4; ++m) {
        int row = wm * 64 + m * 16 + lr;
        int slot = (kk * 4 + lk) ^ (row & 7);
        af[m] = *reinterpret_cast<const bf16x8*>(&As[row * BK + slot * 8]);
      }
#pragma unroll
      for (int n = 0; n < 4; ++n) {
        int row = wn * 64 + n * 16 + lr;
        int slot = (kk * 4 + lk) ^ (row & 7);
        bfr[n] = *reinterpret_cast<const bf16x8*>(&Bs[row * BK + slot * 8]);
      }
#pragma unroll
      for (int m = 0; m < 4; ++m)
#pragma unroll
        for (int n = 0; n < 4; ++n)
          acc[m][n] = __builtin_amdgcn_mfma_f32_16x16x32_bf16(af[m], bfr[n], acc[m][n], 0, 0, 0);
    }
    __syncthreads();
  }

  const int crow0 = bm * 256 + wm * 64;
  const int ccol0 = bn * 128 + wn * 64;
#pragma unroll
  for (int m = 0; m < 4; ++m) {
#pragma unroll
    for (int n = 0; n < 4; ++n) {
#pragma unroll
      for (int r = 0; r < 4; ++r) {
        const int row = crow0 + m * 16 + lk * 4 + r;
        const int col = ccol0 + n * 16 + lr;
        Cout[(size_t)row * D_ + col] = acc[m][n][r] + bias[col];
      }
    }
  }
}

// ---------------------------------------------------------------------------
// Causal flash attention v16: v15 (deferred srow) + P buffer shrunk to
// 64B rows with 16B-slot XOR swizzle (^lr&3). LDS 21504 -> 20480 B exactly
// -> 8 blocks/CU (32 waves/CU, full occupancy). Roundtrip verified:
// write (n,lk,r) at slot_lin=2n+(lk>>1), byte 8(lk&1)+2r; read (lr,lk)
// = slot_lin lk full 16B; both XOR (lr&3). Reads stay 2-way (free);
// the two 8B P-writes go ~4-way (minor) — traded for +1 block/CU.
// ---------------------------------------------------------------------------
__global__ __launch_bounds__(256, 8) void attn_fwd(const bf16* __restrict__ Qh,
                                                   const bf16* __restrict__ Kh,
                                                   const bf16* __restrict__ Vt,
                                                   bf16* __restrict__ ctx) {
  __shared__ __align__(16) bf16 Kbuf[2][32 * 64];   // 8 KB
  __shared__ __align__(16) bf16 Vbuf[2][32 * 64];   // 8 KB
  __shared__ __align__(16) char Ps[4][16 * 64];     // 4 KB

  const int tid = threadIdx.x, w = tid >> 6, l = tid & 63;
  const int lr = l & 15, lk = l >> 4;
  const int bid = blockIdx.x;
  const int head = bid & 63;
  const int t = 31 - (bid >> 6);
  char* Pw = &Ps[w][0];

  const bf16* Qb = Qh + (size_t)head * T_ * DK_;
  const bf16* Kb = Kh + (size_t)head * T_ * DK_;
  const bf16* Vb = Vt + (size_t)head * DK_ * T_;
  const int bb = head >> 4, hh = head & 15;

  const int r0 = t * 64;
  const int nt32 = 2 * (t + 1);
  const int qrow = r0 + w * 16 + lr;
  const int jd = (r0 + w * 16) >> 5;

  const bf16* qp = Qb + (size_t)qrow * DK_ + lk * 8;
  bf16x8 qf0 = *reinterpret_cast<const bf16x8*>(qp);
  bf16x8 qf1 = *reinterpret_cast<const bf16x8*>(qp + 32);

  // hoisted staging pointers
  const int p = tid;
  const int krow = p >> 3, kso = (p & 7) ^ (krow & 7);
  const bf16* kgp = Kb + (size_t)krow * DK_ + kso * 8;
  const int vu = (p & 7) ^ (krow & 7);
  const int vdk = krow * 2 + (vu >> 2);
  const bf16* vgp = Vb + (size_t)vdk * T_ + (vu & 3) * 8;
  bf16* const kl0 = &Kbuf[0][p * 8];
  bf16* const kl1 = &Kbuf[1][p * 8];
  bf16* const vl0 = &Vbuf[0][p * 8];
  bf16* const vl1 = &Vbuf[1][p * 8];

  // hoisted fragment/P offsets (P: 64B rows, 16B-slot XOR ^ (lr&3))
  int qko[2][2], pwo[2], pvo[4];
#pragma unroll
  for (int n = 0; n < 2; ++n) {
    const int row = n * 16 + lr;
    qko[n][0] = row * 64 + ((lk ^ (row & 7)) << 3);
    qko[n][1] = row * 64 + (((4 + lk) ^ (row & 7)) << 3);
    pwo[n] = lr * 64 + (((n * 2 + (lk >> 1)) ^ (lr & 3)) << 4) + (lk & 1) * 8;
  }
  const int pro = lr * 64 + ((lk ^ (lr & 3)) << 4);
#pragma unroll
  for (int n = 0; n < 4; ++n) {
    const int rowp = n * 8 + (lr >> 1);
    const int s = ((lr & 1) * 4 + lk) ^ (rowp & 7);
    pvo[n] = rowp * 64 + s * 8;
  }
  bf16* const cp = &ctx[((size_t)(bb * T_ + qrow)) * D_ + hh * DK_ + lk * 4];

  f32x4 oacc[4] = {};
  float srow = 0.f;                            // private partial (deferred reduce)

  // prologue: stage tile 0
  gld_lds16(kgp, kl0);
  gld_lds16(vgp, vl0);
  kgp += 32 * DK_;
  vgp += 32;
  __syncthreads();

  int buf = 0;
#pragma unroll 1
  for (int j = 0; j < nt32; ++j) {
    if (j + 1 < nt32) {
      gld_lds16(kgp, buf ? kl0 : kl1);
      gld_lds16(vgp, buf ? vl0 : vl1);
      kgp += 32 * DK_;
      vgp += 32;
    }

    if (j <= jd) {
      const bf16* kbase = buf ? &Kbuf[1][0] : &Kbuf[0][0];
      const bf16* vbase = buf ? &Vbuf[1][0] : &Vbuf[0][0];

      f32x4 sacc[2] = {};
      __builtin_amdgcn_s_setprio(1);
#pragma unroll
      for (int n = 0; n < 2; ++n) {
        bf16x8 kf0 = *reinterpret_cast<const bf16x8*>(kbase + qko[n][0]);
        bf16x8 kf1 = *reinterpret_cast<const bf16x8*>(kbase + qko[n][1]);
        sacc[n] = __builtin_amdgcn_mfma_f32_16x16x32_bf16(kf0, qf0, sacc[n], 0, 0, 0);
        sacc[n] = __builtin_amdgcn_mfma_f32_16x16x32_bf16(kf1, qf1, sacc[n], 0, 0, 0);
      }
      __builtin_amdgcn_s_setprio(0);

      if (j == jd) {
#pragma unroll
        for (int n = 0; n < 2; ++n)
#pragma unroll
          for (int r = 0; r < 4; ++r)
            if (j * 32 + n * 16 + lk * 4 + r > qrow) sacc[n][r] = -1e30f;
      }

#pragma unroll
      for (int n = 0; n < 2; ++n) {
        float p0 = __builtin_exp2f(sacc[n][0]);
        float p1 = __builtin_exp2f(sacc[n][1]);
        float p2 = __builtin_exp2f(sacc[n][2]);
        float p3 = __builtin_exp2f(sacc[n][3]);
        srow += (p0 + p1) + (p2 + p3);         // private partial; no shuffles here
        bf16x4 pk;
        pk[0] = bfbits(p0); pk[1] = bfbits(p1); pk[2] = bfbits(p2); pk[3] = bfbits(p3);
        *reinterpret_cast<bf16x4*>(Pw + pwo[n]) = pk;
      }

      bf16x8 pa = *reinterpret_cast<const bf16x8*>(Pw + pro);

      __builtin_amdgcn_s_setprio(1);
#pragma unroll
      for (int n = 0; n < 4; ++n) {
        bf16x8 vf = *reinterpret_cast<const bf16x8*>(vbase + pvo[n]);
        oacc[n] = __builtin_amdgcn_mfma_f32_16x16x32_bf16(vf, pa, oacc[n], 0, 0, 0);
      }
      __builtin_amdgcn_s_setprio(0);
    }

    __syncthreads();
    buf ^= 1;
  }

  // deferred cross-lane reduction (once per task, not per tile)
  srow += __shfl_xor(srow, 16, 64);
  srow += __shfl_xor(srow, 32, 64);

  const float inv = 1.0f / srow;
#pragma unroll
  for (int n = 0; n < 4; ++n) {
    bf16x4 pk;
#pragma unroll
    for (int r = 0; r < 4; ++r) pk[r] = bfbits(oacc[n][r] * inv);
    *reinterpret_cast<bf16x4*>(cp + n * 16) = pk;
  }
}

// ---------------------------------------------------------------------------
// launch
// ---------------------------------------------------------------------------
extern "C" void kernel_launch(void* const* d_in, const int* in_sizes, int n_in,
                              void* d_out, int out_size, void* d_ws, size_t ws_size,
                              hipStream_t stream) {
  const float* q  = (const float*)d_in[0];
  const float* k  = (const float*)d_in[1];
  const float* v  = (const float*)d_in[2];
  const float* Wq = (const float*)d_in[3];
  const float* Wk = (const float*)d_in[4];
  const float* Wv = (const float*)d_in[5];
  const float* Wo = (const float*)d_in[6];
  const float* bq = (const float*)d_in[7];
  const float* bk = (const float*)d_in[8];
  const float* bv = (const float*)d_in[9];
  const float* bo = (const float*)d_in[10];

  constexpr size_t E_IN = (size_t)M_ * D_;
  constexpr size_t E_W  = (size_t)D_ * D_;
  char* ws = (char*)d_ws;
  size_t off = 0;
  bf16* Wqb = (bf16*)(ws + off); off += E_W * 2;
  bf16* Wkb = (bf16*)(ws + off); off += E_W * 2;
  bf16* Wvb = (bf16*)(ws + off); off += E_W * 2;
  bf16* Wob = (bf16*)(ws + off); off += E_W * 2;
  bf16* Qh  = (bf16*)(ws + off); off += E_IN * 2;
  bf16* Kh  = (bf16*)(ws + off); off += E_IN * 2;
  bf16* Vtw = (bf16*)(ws + off); off += E_IN * 2;
  bf16* ctx = (bf16*)(ws + off); off += E_IN * 2;

  cvt_w<<<dim3(4096), dim3(256), 0, stream>>>(Wq, Wk, Wv, Wo, Wqb, Wkb, Wvb, Wob);

  proj_qkv<<<dim3(32, 8, 3), dim3(512), 0, stream>>>(q, k, v, Wqb, Wkb, Wvb,
                                                     bq, bk, bv, Qh, Kh, Vtw);

  attn_fwd<<<dim3(2048), dim3(256), 0, stream>>>(Qh, Kh, Vtw, ctx);

  gemm_out<<<dim3(32, 8), dim3(512), 0, stream>>>(ctx, Wob, bo, (float*)d_out);
}

// Round 23
// 184.432 us; speedup vs baseline: 1.0095x; 1.0095x over previous
//
#include <hip/hip_runtime.h>
#include <hip/hip_bf16.h>
#include <stdint.h>

#define B_ 4
#define T_ 2048
#define D_ 1024
#define H_ 16
#define DK_ 64
#define M_ (B_*T_)   // 8192

typedef __attribute__((ext_vector_type(8))) short bf16x8;
typedef __attribute__((ext_vector_type(4))) short bf16x4;
typedef __attribute__((ext_vector_type(4))) float f32x4;
typedef __hip_bfloat16 bf16;

__device__ __forceinline__ void gld_lds16(const bf16* g, bf16* l) {
  __builtin_amdgcn_global_load_lds((const __attribute__((address_space(1))) void*)g,
                                   (__attribute__((address_space(3))) void*)l,
                                   16, 0, 0);
}
__device__ __forceinline__ void gld_lds16f(const float* g, float* l) {
  __builtin_amdgcn_global_load_lds((const __attribute__((address_space(1))) void*)g,
                                   (__attribute__((address_space(3))) void*)l,
                                   16, 0, 0);
}

__device__ __forceinline__ short bfbits(float f) {
  union { bf16 h; short s; } u; u.h = __float2bfloat16(f); return u.s;
}

// ---------------------------------------------------------------------------
// fp32 -> bf16 convert, WEIGHTS ONLY
// ---------------------------------------------------------------------------
__global__ __launch_bounds__(256) void cvt_w(
    const float* __restrict__ wq, const float* __restrict__ wk,
    const float* __restrict__ wv, const float* __restrict__ wo,
    bf16* __restrict__ wqb, bf16* __restrict__ wkb,
    bf16* __restrict__ wvb, bf16* __restrict__ wob) {
  int gid = blockIdx.x * 256 + threadIdx.x;   // 0 .. 1048575 (float4 units)
  int s = gid >> 18, off = gid & 262143;
  const float* src = (s == 0) ? wq : (s == 1) ? wk : (s == 2) ? wv : wo;
  bf16* dst = (s == 0) ? wqb : (s == 1) ? wkb : (s == 2) ? wvb : wob;
  float4 val = reinterpret_cast<const float4*>(src)[off];
  union { ushort4 u; bf16 h[4]; } o;
  o.h[0] = __float2bfloat16(val.x);
  o.h[1] = __float2bfloat16(val.y);
  o.h[2] = __float2bfloat16(val.z);
  o.h[3] = __float2bfloat16(val.w);
  reinterpret_cast<ushort4*>(dst)[off] = o.u;
}

// ---------------------------------------------------------------------------
// Unified QKV projection: (feature, token) orientation, A = weight bf16 via
// gld_lds (8-slot XOR), B = raw fp32 tokens via gld_lds (16-slot XOR),
// converted per-fragment. 2-phase sync. LDS 64 KB.
// ---------------------------------------------------------------------------
__global__ __launch_bounds__(512) void proj_qkv(
    const float* __restrict__ qf, const float* __restrict__ kf, const float* __restrict__ vf,
    const bf16* __restrict__ Wqb, const bf16* __restrict__ Wkb, const bf16* __restrict__ Wvb,
    const float* __restrict__ bq, const float* __restrict__ bk, const float* __restrict__ bv,
    bf16* __restrict__ Qh, bf16* __restrict__ Kh, bf16* __restrict__ Vt) {
  constexpr int K = 1024;
  constexpr int BK = 64;
  __shared__ __align__(16) bf16  As[256 * 64];
  __shared__ __align__(16) float Bsf[128 * 64];

  const int z = blockIdx.z;
  const bf16*  A  = (z == 0) ? Wqb : (z == 1) ? Wkb : Wvb;
  const float* Bf = (z == 0) ? qf : (z == 1) ? kf : vf;
  const float* bias = (z == 0) ? bq : (z == 1) ? bk : bv;
  bf16* out = (z == 0) ? Qh : (z == 1) ? Kh : Vt;
  const float scale = (z == 0) ? 0.125f * 1.4426950408889634f : 1.0f;

  const int bid = blockIdx.x + 32 * blockIdx.y;
  const int bm = bid >> 6;
  const int bn = bid & 63;

  const int tid = threadIdx.x;
  const int w = tid >> 6, l = tid & 63;
  const int wm = w >> 1, wn = w & 1;
  const int lr = l & 15, lk = l >> 4;

  f32x4 acc[4][4] = {};

  for (int k0 = 0; k0 < K; k0 += BK) {
#pragma unroll
    for (int i = 0; i < 4; ++i) {
      int p = i * 512 + tid;
      int row = p >> 3;
      int so = (p & 7) ^ (row & 7);
      gld_lds16(A + (size_t)(bm * 256 + row) * K + k0 + so * 8, &As[p * 8]);
    }
#pragma unroll
    for (int i = 0; i < 4; ++i) {
      int p = i * 512 + tid;
      int row = p >> 4;
      int sc = (p & 15) ^ (row & 15);
      gld_lds16f(Bf + (size_t)(bn * 128 + row) * K + k0 + sc * 4, &Bsf[p * 4]);
    }
    __syncthreads();

#pragma unroll
    for (int kk = 0; kk < 2; ++kk) {
      bf16x8 af[4], bfr[4];
#pragma unroll
      for (int m = 0; m < 4; ++m) {
        int row = wm * 64 + m * 16 + lr;
        int slot = (kk * 4 + lk) ^ (row & 7);
        af[m] = *reinterpret_cast<const bf16x8*>(&As[row * 64 + slot * 8]);
      }
#pragma unroll
      for (int n = 0; n < 4; ++n) {
        int trow = wn * 64 + n * 16 + lr;
        int c0 = kk * 8 + lk * 2;
        int s0 = c0 ^ (trow & 15);
        int s1 = (c0 + 1) ^ (trow & 15);
        f32x4 lo = *reinterpret_cast<const f32x4*>(&Bsf[trow * 64 + s0 * 4]);
        f32x4 hi = *reinterpret_cast<const f32x4*>(&Bsf[trow * 64 + s1 * 4]);
        bf16x8 bb;
        bb[0] = bfbits(lo[0]); bb[1] = bfbits(lo[1]);
        bb[2] = bfbits(lo[2]); bb[3] = bfbits(lo[3]);
        bb[4] = bfbits(hi[0]); bb[5] = bfbits(hi[1]);
        bb[6] = bfbits(hi[2]); bb[7] = bfbits(hi[3]);
        bfr[n] = bb;
      }
      __builtin_amdgcn_s_setprio(1);
#pragma unroll
      for (int m = 0; m < 4; ++m)
#pragma unroll
        for (int n = 0; n < 4; ++n)
          acc[m][n] = __builtin_amdgcn_mfma_f32_16x16x32_bf16(af[m], bfr[n], acc[m][n], 0, 0, 0);
      __builtin_amdgcn_s_setprio(0);
    }
    __syncthreads();
  }

  const int crow0 = bm * 256 + wm * 64;
  const int ccol0 = bn * 128 + wn * 64;
  if (z < 2) {
#pragma unroll
    for (int m = 0; m < 4; ++m) {
#pragma unroll
      for (int n = 0; n < 4; ++n) {
        const int row0 = crow0 + m * 16 + lk * 4;
        const int col = ccol0 + n * 16 + lr;
        bf16x4 pk;
#pragma unroll
        for (int r = 0; r < 4; ++r)
          pk[r] = bfbits((acc[m][n][r] + bias[row0 + r]) * scale);
        size_t idx = (((size_t)(col >> 11) * H_ + (row0 >> 6)) * T_ + (col & (T_ - 1))) * DK_ + (row0 & 63);
        *reinterpret_cast<bf16x4*>(&out[idx]) = pk;
      }
    }
  } else {
#pragma unroll
    for (int m = 0; m < 4; ++m) {
#pragma unroll
      for (int n = 0; n < 4; ++n) {
#pragma unroll
        for (int r = 0; r < 4; ++r) {
          const int row = crow0 + m * 16 + lk * 4 + r;
          const int col = ccol0 + n * 16 + lr;
          float vv = acc[m][n][r] + bias[row];
          size_t idx = (size_t)(col >> 11) * ((size_t)H_ * DK_ * T_) + (size_t)row * T_ + (col & (T_ - 1));
          out[idx] = __float2bfloat16(vv);
        }
      }
    }
  }
}

// ---------------------------------------------------------------------------
// Output GEMM (fp32 out), 256x128 tile, 512 threads
// ---------------------------------------------------------------------------
__global__ __launch_bounds__(512) void gemm_out(const bf16* __restrict__ A,
                                                const bf16* __restrict__ Bm,
                                                const float* __restrict__ bias,
                                                float* __restrict__ Cout) {
  constexpr int K = 1024;
  constexpr int BK = 64;
  __shared__ __align__(16) bf16 As[256 * BK];
  __shared__ __align__(16) bf16 Bs[128 * BK];

  const int bid = blockIdx.x + 32 * blockIdx.y;
  const int xcd = bid & 7, loc = bid >> 3;
  const int bm = xcd * 4 + (loc & 3);
  const int bn = loc >> 2;

  const int tid = threadIdx.x;
  const int w = tid >> 6, l = tid & 63;
  const int wm = w >> 1, wn = w & 1;
  const int lr = l & 15, lk = l >> 4;

  f32x4 acc[4][4] = {};

  for (int k0 = 0; k0 < K; k0 += BK) {
#pragma unroll
    for (int i = 0; i < 4; ++i) {
      int p = i * 512 + tid;
      int row = p >> 3;
      int so = (p & 7) ^ (row & 7);
      gld_lds16(A + (size_t)(bm * 256 + row) * K + k0 + so * 8, &As[p * 8]);
    }
#pragma unroll
    for (int i = 0; i < 2; ++i) {
      int p = i * 512 + tid;
      int row = p >> 3;
      int so = (p & 7) ^ (row & 7);
      gld_lds16(Bm + (size_t)(bn * 128 + row) * K + k0 + so * 8, &Bs[p * 8]);
    }
    __syncthreads();

#pragma unroll
    for (int kk = 0; kk < 2; ++kk) {
      bf16x8 af[4], bfr[4];
#pragma unroll
      for (int m = 0; m < 4; ++m) {
        int row = wm * 64 + m * 16 + lr;
        int slot = (kk * 4 + lk) ^ (row & 7);
        af[m] = *reinterpret_cast<const bf16x8*>(&As[row * BK + slot * 8]);
      }
#pragma unroll
      for (int n = 0; n < 4; ++n) {
        int row = wn * 64 + n * 16 + lr;
        int slot = (kk * 4 + lk) ^ (row & 7);
        bfr[n] = *reinterpret_cast<const bf16x8*>(&Bs[row * BK + slot * 8]);
      }
#pragma unroll
      for (int m = 0; m < 4; ++m)
#pragma unroll
        for (int n = 0; n < 4; ++n)
          acc[m][n] = __builtin_amdgcn_mfma_f32_16x16x32_bf16(af[m], bfr[n], acc[m][n], 0, 0, 0);
    }
    __syncthreads();
  }

  const int crow0 = bm * 256 + wm * 64;
  const int ccol0 = bn * 128 + wn * 64;
#pragma unroll
  for (int m = 0; m < 4; ++m) {
#pragma unroll
    for (int n = 0; n < 4; ++n) {
#pragma unroll
      for (int r = 0; r < 4; ++r) {
        const int row = crow0 + m * 16 + lk * 4 + r;
        const int col = ccol0 + n * 16 + lr;
        Cout[(size_t)row * D_ + col] = acc[m][n][r] + bias[col];
      }
    }
  }
}

// ---------------------------------------------------------------------------
// Causal flash attention v15 (round-21 exact): 7 blocks/CU, KVBLK=32,
// hoisted addressing, fixed-shift softmax, DEFERRED srow reduction.
// ---------------------------------------------------------------------------
__global__ __launch_bounds__(256, 7) void attn_fwd(const bf16* __restrict__ Qh,
                                                   const bf16* __restrict__ Kh,
                                                   const bf16* __restrict__ Vt,
                                                   bf16* __restrict__ ctx) {
  __shared__ __align__(16) bf16 Kbuf[2][32 * 64];
  __shared__ __align__(16) bf16 Vbuf[2][32 * 64];
  __shared__ __align__(16) char Ps[4][16 * 80];

  const int tid = threadIdx.x, w = tid >> 6, l = tid & 63;
  const int lr = l & 15, lk = l >> 4;
  const int bid = blockIdx.x;
  const int head = bid & 63;
  const int t = 31 - (bid >> 6);
  char* Pw = &Ps[w][0];

  const bf16* Qb = Qh + (size_t)head * T_ * DK_;
  const bf16* Kb = Kh + (size_t)head * T_ * DK_;
  const bf16* Vb = Vt + (size_t)head * DK_ * T_;
  const int bb = head >> 4, hh = head & 15;

  const int r0 = t * 64;
  const int nt32 = 2 * (t + 1);
  const int qrow = r0 + w * 16 + lr;
  const int jd = (r0 + w * 16) >> 5;

  const bf16* qp = Qb + (size_t)qrow * DK_ + lk * 8;
  bf16x8 qf0 = *reinterpret_cast<const bf16x8*>(qp);
  bf16x8 qf1 = *reinterpret_cast<const bf16x8*>(qp + 32);

  // hoisted staging pointers
  const int p = tid;
  const int krow = p >> 3, kso = (p & 7) ^ (krow & 7);
  const bf16* kgp = Kb + (size_t)krow * DK_ + kso * 8;
  const int vu = (p & 7) ^ (krow & 7);
  const int vdk = krow * 2 + (vu >> 2);
  const bf16* vgp = Vb + (size_t)vdk * T_ + (vu & 3) * 8;
  bf16* const kl0 = &Kbuf[0][p * 8];
  bf16* const kl1 = &Kbuf[1][p * 8];
  bf16* const vl0 = &Vbuf[0][p * 8];
  bf16* const vl1 = &Vbuf[1][p * 8];

  // hoisted fragment/P offsets
  int qko[2][2], pwo[2], pvo[4];
#pragma unroll
  for (int n = 0; n < 2; ++n) {
    const int row = n * 16 + lr;
    qko[n][0] = row * 64 + ((lk ^ (row & 7)) << 3);
    qko[n][1] = row * 64 + (((4 + lk) ^ (row & 7)) << 3);
    pwo[n] = lr * 80 + n * 32 + lk * 8;
  }
  const int pro = lr * 80 + lk * 16;
#pragma unroll
  for (int n = 0; n < 4; ++n) {
    const int rowp = n * 8 + (lr >> 1);
    const int s = ((lr & 1) * 4 + lk) ^ (rowp & 7);
    pvo[n] = rowp * 64 + s * 8;
  }
  bf16* const cp = &ctx[((size_t)(bb * T_ + qrow)) * D_ + hh * DK_ + lk * 4];

  f32x4 oacc[4] = {};
  float srow = 0.f;                            // private partial (deferred reduce)

  // prologue: stage tile 0
  gld_lds16(kgp, kl0);
  gld_lds16(vgp, vl0);
  kgp += 32 * DK_;
  vgp += 32;
  __syncthreads();

  int buf = 0;
#pragma unroll 1
  for (int j = 0; j < nt32; ++j) {
    if (j + 1 < nt32) {
      gld_lds16(kgp, buf ? kl0 : kl1);
      gld_lds16(vgp, buf ? vl0 : vl1);
      kgp += 32 * DK_;
      vgp += 32;
    }

    if (j <= jd) {
      const bf16* kbase = buf ? &Kbuf[1][0] : &Kbuf[0][0];
      const bf16* vbase = buf ? &Vbuf[1][0] : &Vbuf[0][0];

      f32x4 sacc[2] = {};
      __builtin_amdgcn_s_setprio(1);
#pragma unroll
      for (int n = 0; n < 2; ++n) {
        bf16x8 kf0 = *reinterpret_cast<const bf16x8*>(kbase + qko[n][0]);
        bf16x8 kf1 = *reinterpret_cast<const bf16x8*>(kbase + qko[n][1]);
        sacc[n] = __builtin_amdgcn_mfma_f32_16x16x32_bf16(kf0, qf0, sacc[n], 0, 0, 0);
        sacc[n] = __builtin_amdgcn_mfma_f32_16x16x32_bf16(kf1, qf1, sacc[n], 0, 0, 0);
      }
      __builtin_amdgcn_s_setprio(0);

      if (j == jd) {
#pragma unroll
        for (int n = 0; n < 2; ++n)
#pragma unroll
          for (int r = 0; r < 4; ++r)
            if (j * 32 + n * 16 + lk * 4 + r > qrow) sacc[n][r] = -1e30f;
      }

#pragma unroll
      for (int n = 0; n < 2; ++n) {
        float p0 = __builtin_exp2f(sacc[n][0]);
        float p1 = __builtin_exp2f(sacc[n][1]);
        float p2 = __builtin_exp2f(sacc[n][2]);
        float p3 = __builtin_exp2f(sacc[n][3]);
        srow += (p0 + p1) + (p2 + p3);         // private partial; no shuffles here
        bf16x4 pk;
        pk[0] = bfbits(p0); pk[1] = bfbits(p1); pk[2] = bfbits(p2); pk[3] = bfbits(p3);
        *reinterpret_cast<bf16x4*>(Pw + pwo[n]) = pk;
      }

      bf16x8 pa = *reinterpret_cast<const bf16x8*>(Pw + pro);

      __builtin_amdgcn_s_setprio(1);
#pragma unroll
      for (int n = 0; n < 4; ++n) {
        bf16x8 vf = *reinterpret_cast<const bf16x8*>(vbase + pvo[n]);
        oacc[n] = __builtin_amdgcn_mfma_f32_16x16x32_bf16(vf, pa, oacc[n], 0, 0, 0);
      }
      __builtin_amdgcn_s_setprio(0);
    }

    __syncthreads();
    buf ^= 1;
  }

  // deferred cross-lane reduction (once per task, not per tile)
  srow += __shfl_xor(srow, 16, 64);
  srow += __shfl_xor(srow, 32, 64);

  const float inv = 1.0f / srow;
#pragma unroll
  for (int n = 0; n < 4; ++n) {
    bf16x4 pk;
#pragma unroll
    for (int r = 0; r < 4; ++r) pk[r] = bfbits(oacc[n][r] * inv);
    *reinterpret_cast<bf16x4*>(cp + n * 16) = pk;
  }
}

// ---------------------------------------------------------------------------
// launch
// ---------------------------------------------------------------------------
extern "C" void kernel_launch(void* const* d_in, const int* in_sizes, int n_in,
                              void* d_out, int out_size, void* d_ws, size_t ws_size,
                              hipStream_t stream) {
  const float* q  = (const float*)d_in[0];
  const float* k  = (const float*)d_in[1];
  const float* v  = (const float*)d_in[2];
  const float* Wq = (const float*)d_in[3];
  const float* Wk = (const float*)d_in[4];
  const float* Wv = (const float*)d_in[5];
  const float* Wo = (const float*)d_in[6];
  const float* bq = (const float*)d_in[7];
  const float* bk = (const float*)d_in[8];
  const float* bv = (const float*)d_in[9];
  const float* bo = (const float*)d_in[10];

  constexpr size_t E_IN = (size_t)M_ * D_;
  constexpr size_t E_W  = (size_t)D_ * D_;
  char* ws = (char*)d_ws;
  size_t off = 0;
  bf16* Wqb = (bf16*)(ws + off); off += E_W * 2;
  bf16* Wkb = (bf16*)(ws + off); off += E_W * 2;
  bf16* Wvb = (bf16*)(ws + off); off += E_W * 2;
  bf16* Wob = (bf16*)(ws + off); off += E_W * 2;
  bf16* Qh  = (bf16*)(ws + off); off += E_IN * 2;
  bf16* Kh  = (bf16*)(ws + off); off += E_IN * 2;
  bf16* Vtw = (bf16*)(ws + off); off += E_IN * 2;
  bf16* ctx = (bf16*)(ws + off); off += E_IN * 2;

  cvt_w<<<dim3(4096), dim3(256), 0, stream>>>(Wq, Wk, Wv, Wo, Wqb, Wkb, Wvb, Wob);

  proj_qkv<<<dim3(32, 8, 3), dim3(512), 0, stream>>>(q, k, v, Wqb, Wkb, Wvb,
                                                     bq, bk, bv, Qh, Kh, Vtw);

  attn_fwd<<<dim3(2048), dim3(256), 0, stream>>>(Qh, Kh, Vtw, ctx);

  gemm_out<<<dim3(32, 8), dim3(512), 0, stream>>>(ctx, Wob, bo, (float*)d_out);
}